// Round 11
// baseline (155.052 us; speedup 1.0000x reference)
//
#include <hip/hip_runtime.h>
#include <hip/hip_fp16.h>

#define HEADS 4
#define DH    32
#define HW    4096
#define CIN   256
#define HID   128
#define KSPLIT 2
#define KHALF (HW / KSPLIT)
#define NIT   (KHALF / 64)

using half8    = __attribute__((ext_vector_type(8))) _Float16;
using half4    = __attribute__((ext_vector_type(4))) _Float16;
using half2v   = __attribute__((ext_vector_type(2))) _Float16;
using floatx4  = __attribute__((ext_vector_type(4))) float;
using floatx16 = __attribute__((ext_vector_type(16))) float;
using uint4v   = __attribute__((ext_vector_type(4))) unsigned;

// P = exp2(s_log2 - 3*log2e); log2(e) folded into Q pre-scale, shift folded
// into the S-MFMA C-initializer. Fixed shift (no running max) => split-K
// partials combine by pure addition.
#define SHIFT2 4.328085122666891f
#define WQSCALE 0.25508275947f   // 32^-0.5 * log2(e)

static __device__ __forceinline__ unsigned pkr(float a, float b) {
  return __builtin_bit_cast(unsigned, __builtin_amdgcn_cvt_pkrtz(a, b));
}

// ---------------------------------------------------------------------------
// qkv_fused: m-merged (R6). grid (2,256): each block computes 3 m-tiles for
// its 64 pixels; x read 2x. w_qkv is L2-resident so re-reading W is ~free.
// ---------------------------------------------------------------------------
__global__ __launch_bounds__(256) void qkv_fused(
    const float* __restrict__ w, const float* __restrict__ x,
    _Float16* __restrict__ Qw, _Float16* __restrict__ Kw,
    _Float16* __restrict__ Vtw)
{
  __shared__ float t[64][65];
  __shared__ _Float16 As[64][72];
  __shared__ _Float16 Bs[64][72];
  const int mg = blockIdx.x, nt = blockIdx.y;
  const int b = nt >> 6, p0 = (nt & 63) * 64;
  const int tid = threadIdx.x;
  const int wv = tid >> 6, lane = tid & 63, lm = lane & 15, quad = lane >> 4;

  const float* xb = x + (size_t)b * CIN * HW + p0;

  floatx4 acc[3][4] = {{{0,0,0,0},{0,0,0,0},{0,0,0,0},{0,0,0,0}},
                       {{0,0,0,0},{0,0,0,0},{0,0,0,0},{0,0,0,0}},
                       {{0,0,0,0},{0,0,0,0},{0,0,0,0},{0,0,0,0}}};

  for (int kq = 0; kq < 4; ++kq) {
    __syncthreads();   // t & Bs free (prev kq consumers done)
    #pragma unroll
    for (int i = 0; i < 4; ++i) {
      int ci = tid + i * 256;
      int cc = ci >> 4, p4 = (ci & 15) * 4;
      *(float4*)&t[cc][p4] =
          *(const float4*)(xb + (size_t)(kq * 64 + cc) * HW + p4);
    }
    __syncthreads();   // t ready
    #pragma unroll
    for (int i = 0; i < 2; ++i) {
      int idx = tid + i * 256;
      int p = idx >> 3, c0 = (idx & 7) * 8;
      half8 v;
      #pragma unroll
      for (int k = 0; k < 8; ++k) v[k] = (_Float16)t[c0 + k][p];
      *(half8*)&Bs[p][c0] = v;
    }

    #pragma unroll
    for (int im = 0; im < 3; ++im) {
      const int mt = mg * 3 + im;
      const float wscale = (mt < 2) ? WQSCALE : 1.0f;
      const float* Ag = w + (size_t)(mt * 64) * CIN;
      __syncthreads();   // Bs ready (im=0) / As free (im>0)
      #pragma unroll
      for (int i = 0; i < 2; ++i) {
        int ci = tid + i * 256;
        int r = ci >> 3, c8 = (ci & 7) * 8;
        const float* src = Ag + (size_t)r * CIN + kq * 64 + c8;
        float4 u0 = *(const float4*)(src);
        float4 u1 = *(const float4*)(src + 4);
        half8 h = {(_Float16)(u0.x * wscale), (_Float16)(u0.y * wscale),
                   (_Float16)(u0.z * wscale), (_Float16)(u0.w * wscale),
                   (_Float16)(u1.x * wscale), (_Float16)(u1.y * wscale),
                   (_Float16)(u1.z * wscale), (_Float16)(u1.w * wscale)};
        *(half8*)&As[r][c8] = h;
      }
      __syncthreads();   // As ready
      #pragma unroll
      for (int ks = 0; ks < 2; ++ks) {
        half8 a = *(const half8*)&As[wv * 16 + lm][ks * 32 + quad * 8];
        #pragma unroll
        for (int ns = 0; ns < 4; ++ns) {
          half8 bf = *(const half8*)&Bs[ns * 16 + lm][ks * 32 + quad * 8];
          acc[im][ns] = __builtin_amdgcn_mfma_f32_16x16x32_f16(a, bf, acc[im][ns], 0, 0, 0);
        }
      }
    }
  }

  #pragma unroll
  for (int im = 0; im < 3; ++im) {
    const int mt = mg * 3 + im;
    const int sec = mt >> 1;                    // 0=Q 1=K 2=V
    const int o_base = (mt & 1) * 64 + wv * 16 + quad * 4;
    const int hh = o_base >> 5, dd = o_base & 31;
    const int bh = b * HEADS + hh;
    if (sec < 2) {
      _Float16* dst = (sec == 0) ? Qw : Kw;
      #pragma unroll
      for (int ns = 0; ns < 4; ++ns) {
        int p = p0 + ns * 16 + lm;
        half4 v = {(_Float16)acc[im][ns][0], (_Float16)acc[im][ns][1],
                   (_Float16)acc[im][ns][2], (_Float16)acc[im][ns][3]};
        *(half4*)(dst + ((size_t)bh * HW + p) * DH + dd) = v;
      }
    } else {
      #pragma unroll
      for (int ns = 0; ns < 4; ++ns) {
        int p = p0 + ns * 16 + lm;
        #pragma unroll
        for (int r = 0; r < 4; ++r)
          Vtw[((size_t)bh * DH + dd + r) * HW + p] = (_Float16)acc[im][ns][r];
      }
    }
  }
}

// ---------------------------------------------------------------------------
// attn: EXACT R8 structure (VALU lsum + shfl_xor, split-K x2) with ONE
// change — bisecting R9's failure: XOR keys now mix row bit 3 so they are
// distinct across rows {0,8,16,24} as well as rows 0-7:
//   K: key(r) = ((r>>1)^(r>>3))&3   (write row kr, read row t*32+l31 —
//      t*32 only touches bit 5, so both sides compute the same key)
//   V: key(r) = (r^(r>>3))&7
// If R8's residual 2^22 conflict cycles came from strided b128 phase
// grouping (lanes l==j mod 8), these keys eliminate them; if the counter
// doesn't move, that hypothesis is dead. If this round NaNs, the keys were
// R9's bug (not the lacc trick) despite the consistency proof.
// grid (32 q-tiles, 16 bh, 2 k-halves) x 256.
// ---------------------------------------------------------------------------
__global__ __launch_bounds__(256) void attn(
    const _Float16* __restrict__ Qw, const _Float16* __restrict__ Kw,
    const _Float16* __restrict__ Vtw, float* __restrict__ Op,
    float* __restrict__ lp)
{
  __shared__ _Float16 ks[2][64][32];          // [phase][k][d]  8 KB
  __shared__ _Float16 vt[2][32][64];          // [phase][d][k]  8 KB

  const int bh = blockIdx.y, qt = blockIdx.x, z = blockIdx.z;
  const int tid = threadIdx.x;
  const int wv = tid >> 6, lane = tid & 63;
  const int l31 = lane & 31, hi = lane >> 5;

  const _Float16* qbase =
      Qw + ((size_t)bh * HW + qt * 128 + wv * 32 + l31) * DH + hi * 8;
  const half8 qb0 = *(const half8*)qbase;        // d = hi*8 + 0..7
  const half8 qb1 = *(const half8*)(qbase + 16); // d = 16 + hi*8 + 0..7

  const floatx16 shift16 = {-SHIFT2,-SHIFT2,-SHIFT2,-SHIFT2,
                            -SHIFT2,-SHIFT2,-SHIFT2,-SHIFT2,
                            -SHIFT2,-SHIFT2,-SHIFT2,-SHIFT2,
                            -SHIFT2,-SHIFT2,-SHIFT2,-SHIFT2};
  floatx16 oT = {0,0,0,0,0,0,0,0,0,0,0,0,0,0,0,0};
  float lsum = 0.0f;

  const _Float16* kbase = Kw  + (size_t)bh * HW * DH + (size_t)z * KHALF * DH;
  const _Float16* vbase = Vtw + (size_t)bh * DH * HW + (size_t)z * KHALF;
  // staging: K row kr = tid>>2 (4 thr/row, 16B each); V row vr = tid>>3
  const int kr = tid >> 2, kls = tid & 3;              // K logical slot
  const int vr = tid >> 3, vls = tid & 7;              // V logical slot
  const int kps = (kls ^ (((kr >> 1) ^ (kr >> 3)) & 3)) * 8;  // K phys col
  const int vps = (vls ^ ((vr ^ (vr >> 3)) & 7)) * 8;         // V phys col
  const int kc = kls * 8, vc = vls * 8;                // global offsets

  // read-side XOR keys (K row = t*32+l31: key uses bits 1-4 only, so t
  // drops out; V row = l31)
  const int krk = ((l31 >> 1) ^ (l31 >> 3)) & 3;
  const int vrk = (l31 ^ (l31 >> 3)) & 7;

  half8 kA = *(const half8*)(kbase + (size_t)kr * DH + kc);
  half8 vA = *(const half8*)(vbase + (size_t)vr * HW + vc);
  *(half8*)&ks[0][kr][kps] = kA;
  *(half8*)&vt[0][vr][vps] = vA;
  kA = *(const half8*)(kbase + ((size_t)64 + kr) * DH + kc);
  vA = *(const half8*)(vbase + (size_t)vr * HW + 64 + vc);
  __syncthreads();

  for (int it = 0; it < NIT; ++it) {
    const int ph = it & 1, nx = ph ^ 1;

    half8 ka[2][2];
    half8 va[4];
    #pragma unroll
    for (int t = 0; t < 2; ++t)
      #pragma unroll
      for (int d = 0; d < 2; ++d)
        ka[t][d] = *(const half8*)&ks[ph][t * 32 + l31][((d * 2 + hi) ^ krk) * 8];
    #pragma unroll
    for (int k4 = 0; k4 < 4; ++k4)
      va[k4] = *(const half8*)&vt[ph][l31][((k4 * 2 + hi) ^ vrk) * 8];

    *(half8*)&ks[nx][kr][kps] = kA;
    *(half8*)&vt[nx][vr][vps] = vA;
    size_t koff = (size_t)(it + 2) * 64;
    if (koff > KHALF - 64) koff = KHALF - 64;
    kA = *(const half8*)(kbase + (koff + kr) * DH + kc);
    vA = *(const half8*)(vbase + (size_t)vr * HW + koff + vc);

    #pragma unroll
    for (int t = 0; t < 2; ++t) {
      floatx16 sT = __builtin_amdgcn_mfma_f32_32x32x16_f16(ka[t][0], qb0, shift16, 0, 0, 0);
      sT = __builtin_amdgcn_mfma_f32_32x32x16_f16(ka[t][1], qb1, sT, 0, 0, 0);
      float e[16];
      #pragma unroll
      for (int r = 0; r < 16; ++r) e[r] = __builtin_amdgcn_exp2f(sT[r]);
      lsum += (((e[0]+e[1])+(e[2]+e[3]))+((e[4]+e[5])+(e[6]+e[7])))
            + (((e[8]+e[9])+(e[10]+e[11]))+((e[12]+e[13])+(e[14]+e[15])));
      unsigned w0 = pkr(e[0],  e[1]),  w1 = pkr(e[2],  e[3]);
      unsigned w2 = pkr(e[4],  e[5]),  w3 = pkr(e[6],  e[7]);
      unsigned w4 = pkr(e[8],  e[9]),  w5 = pkr(e[10], e[11]);
      unsigned w6 = pkr(e[12], e[13]), w7 = pkr(e[14], e[15]);
      asm("v_permlane32_swap_b32 %0, %1" : "+v"(w0), "+v"(w2));
      asm("v_permlane32_swap_b32 %0, %1" : "+v"(w1), "+v"(w3));
      asm("v_permlane32_swap_b32 %0, %1" : "+v"(w4), "+v"(w6));
      asm("v_permlane32_swap_b32 %0, %1" : "+v"(w5), "+v"(w7));
      uint4v lo4 = {w0, w1, w2, w3}, hi4 = {w4, w5, w6, w7};
      half8 pbLo = __builtin_bit_cast(half8, lo4);
      half8 pbHi = __builtin_bit_cast(half8, hi4);
      oT = __builtin_amdgcn_mfma_f32_32x32x16_f16(va[2*t],     pbLo, oT, 0, 0, 0);
      oT = __builtin_amdgcn_mfma_f32_32x32x16_f16(va[2*t + 1], pbHi, oT, 0, 0, 0);
    }
    __syncthreads();
  }

  lsum += __shfl_xor(lsum, 32, 64);
  const int b = bh >> 2, hh = bh & 3;
  const int row = qt * 128 + wv * 32 + l31;
  float* obase = Op + ((size_t)z * 4 * HW + (size_t)b * HW + row) * HID + hh * DH;
  #pragma unroll
  for (int r0 = 0; r0 < 4; ++r0) {
    float4 v = {oT[4*r0], oT[4*r0+1], oT[4*r0+2], oT[4*r0+3]};
    *(float4*)(obase + 8 * r0 + 4 * hi) = v;
  }
  if (lane < 32)
    lp[(size_t)z * HEADS * 4 * HW + (size_t)bh * HW + row] = lsum;
}

// ---------------------------------------------------------------------------
// out_gemm: m-merged + split-K combine folded into B-staging (R6). grid
// (2,256): B staged once (combined f32 partials, normalized, cvt f16), then
// 2 m-tiles re-staging only As from L2-resident w_out.
// ---------------------------------------------------------------------------
__global__ __launch_bounds__(256) void out_gemm(
    const float* __restrict__ wo, const float* __restrict__ Op,
    const float* __restrict__ lp, const float* __restrict__ bo,
    float* __restrict__ out)
{
  __shared__ _Float16 As[64][136];
  __shared__ _Float16 Bs[64][136];
  __shared__ float inv_l[64][4];
  const int mg = blockIdx.x, nt = blockIdx.y;
  const int b = nt >> 6, p0 = (nt & 63) * 64;
  const int tid = threadIdx.x;
  const int wv = tid >> 6, lane = tid & 63, lm = lane & 15, quad = lane >> 4;

  // combine row sums: inv_l[p][head] = 1/(l_z0 + l_z1)
  {
    const int p = tid >> 2, hh = tid & 3;
    const size_t qi = (size_t)(b * HEADS + hh) * HW + p0 + p;
    inv_l[p][hh] = 1.0f / (lp[qi] + lp[(size_t)HEADS * 4 * HW + qi]);
  }
  __syncthreads();

  const float* Bp0 = Op + ((size_t)b * HW + p0) * HID;          // z = 0
  const float* Bp1 = Bp0 + (size_t)4 * HW * HID;                // z = 1

  // stage combined B tile once
  #pragma unroll
  for (int i = 0; i < 4; ++i) {
    int ci = tid + i * 256;
    int r = ci >> 4, c8 = (ci & 15) * 8;
    const float* s0 = Bp0 + (size_t)r * HID + c8;
    const float* s1 = Bp1 + (size_t)r * HID + c8;
    float4 o0 = *(const float4*)(s0);
    float4 o1 = *(const float4*)(s0 + 4);
    float4 o2 = *(const float4*)(s1);
    float4 o3 = *(const float4*)(s1 + 4);
    const float sc = inv_l[r][c8 >> 5];   // 8 cols stay within one head
    half8 hb = {(_Float16)((o0.x + o2.x) * sc), (_Float16)((o0.y + o2.y) * sc),
                (_Float16)((o0.z + o2.z) * sc), (_Float16)((o0.w + o2.w) * sc),
                (_Float16)((o1.x + o3.x) * sc), (_Float16)((o1.y + o3.y) * sc),
                (_Float16)((o1.z + o3.z) * sc), (_Float16)((o1.w + o3.w) * sc)};
    *(half8*)&Bs[r][c8] = hb;
  }

  #pragma unroll
  for (int im = 0; im < 2; ++im) {
    const int mt = mg * 2 + im;
    const float* Ag = wo + (size_t)(mt * 64) * HID;
    __syncthreads();   // Bs ready (im=0) / As free (im=1)
    #pragma unroll
    for (int i = 0; i < 4; ++i) {
      int ci = tid + i * 256;
      int r = ci >> 4, c8 = (ci & 15) * 8;
      const float* src = Ag + (size_t)r * HID + c8;
      float4 u0 = *(const float4*)(src);
      float4 u1 = *(const float4*)(src + 4);
      half8 h = {(_Float16)u0.x, (_Float16)u0.y, (_Float16)u0.z, (_Float16)u0.w,
                 (_Float16)u1.x, (_Float16)u1.y, (_Float16)u1.z, (_Float16)u1.w};
      *(half8*)&As[r][c8] = h;
    }
    __syncthreads();   // As ready

    floatx4 acc[4] = {{0,0,0,0},{0,0,0,0},{0,0,0,0},{0,0,0,0}};
    #pragma unroll
    for (int ks = 0; ks < 4; ++ks) {
      half8 a = *(const half8*)&As[wv * 16 + lm][ks * 32 + quad * 8];
      #pragma unroll
      for (int ns = 0; ns < 4; ++ns) {
        half8 bf = *(const half8*)&Bs[ns * 16 + lm][ks * 32 + quad * 8];
        acc[ns] = __builtin_amdgcn_mfma_f32_16x16x32_f16(a, bf, acc[ns], 0, 0, 0);
      }
    }

    // direct stores: C[o][p], o = mt*64 + wv*16 + quad*4 + r, p = p0 + ns*16 + lm
    const int o_loc = wv * 16 + quad * 4;
    #pragma unroll
    for (int r = 0; r < 4; ++r) {
      const int o = mt * 64 + o_loc + r;
      const float bias = bo[o];
      float* dst = out + ((size_t)(b * CIN + o)) * HW + p0 + lm;
      #pragma unroll
      for (int ns = 0; ns < 4; ++ns)
        dst[ns * 16] = acc[ns][r] + bias;
    }
  }
}

// ---------------------------------------------------------------------------
extern "C" void kernel_launch(void* const* d_in, const int* in_sizes, int n_in,
                              void* d_out, int out_size, void* d_ws, size_t ws_size,
                              hipStream_t stream)
{
  const float* x     = (const float*)d_in[0];   // [4,256,64,64]
  const float* w_qkv = (const float*)d_in[1];   // [384,256]
  const float* w_out = (const float*)d_in[2];   // [256,128]
  const float* b_out = (const float*)d_in[3];   // [256]
  float* out = (float*)d_out;

  char* ws = (char*)d_ws;
  _Float16* Qw  = (_Float16*)(ws);               //  4 MB [bh][p][d], log2e-scaled
  _Float16* Kw  = (_Float16*)(ws + (4u  << 20)); //  4 MB [bh][p][d]
  _Float16* Vtw = (_Float16*)(ws + (8u  << 20)); //  4 MB [bh][d][p]
  float*    Op  = (float*)   (ws + (12u << 20)); // 16 MB [2][4][4096][128] f32
  float*    lp  = (float*)   (ws + (28u << 20)); // 0.5MB [2][16][4096] f32

  dim3 blk(256);
  qkv_fused<<<dim3(2, 256), blk, 0, stream>>>(w_qkv, x, Qw, Kw, Vtw);
  attn<<<dim3(32, 16, KSPLIT), blk, 0, stream>>>(Qw, Kw, Vtw, Op, lp);
  out_gemm<<<dim3(2, 256), blk, 0, stream>>>(w_out, Op, lp, b_out, out);
}

// Round 12
// 153.266 us; speedup vs baseline: 1.0117x; 1.0117x over previous
//
#include <hip/hip_runtime.h>
#include <hip/hip_fp16.h>

#define HEADS 4
#define DH    32
#define HW    4096
#define CIN   256
#define HID   128
#define KSPLIT 2
#define KHALF (HW / KSPLIT)
#define NIT   (KHALF / 64)

using half8    = __attribute__((ext_vector_type(8))) _Float16;
using half4    = __attribute__((ext_vector_type(4))) _Float16;
using half2v   = __attribute__((ext_vector_type(2))) _Float16;
using floatx4  = __attribute__((ext_vector_type(4))) float;
using floatx16 = __attribute__((ext_vector_type(16))) float;
using uint4v   = __attribute__((ext_vector_type(4))) unsigned;

// P = exp2(s_log2 - 3*log2e); log2(e) folded into Q pre-scale, shift folded
// into the S-MFMA C-initializer. Fixed shift (no running max) => split-K
// partials combine by pure addition.
#define SHIFT2 4.328085122666891f
#define WQSCALE 0.25508275947f   // 32^-0.5 * log2(e)

static __device__ __forceinline__ unsigned pkr(float a, float b) {
  return __builtin_bit_cast(unsigned, __builtin_amdgcn_cvt_pkrtz(a, b));
}

// ---------------------------------------------------------------------------
// qkv_fused v3: THIS ROUND — staging machinery cut. Old: As weight tile
// round-tripped through LDS per m-tile (2 barriers x 3 im) and Bs fragments
// re-read per m-tile (24 b128) -> 8 barriers/kq. New: A-fragments built in
// registers straight from L2-hot w_qkv (float4 pairs + cvt, identical values
// to the old LDS path), Bs fragments hoisted ONCE into 8 regs and reused
// across all 3 m-tiles. 2 barriers/kq (t-ready, Bs-ready); As array deleted
// (LDS 35 -> 26 KB). x transpose via t[64][65] unchanged. grid (2,256).
// ---------------------------------------------------------------------------
__global__ __launch_bounds__(256) void qkv_fused(
    const float* __restrict__ w, const float* __restrict__ x,
    _Float16* __restrict__ Qw, _Float16* __restrict__ Kw,
    _Float16* __restrict__ Vtw)
{
  __shared__ float t[64][65];
  __shared__ _Float16 Bs[64][72];
  const int mg = blockIdx.x, nt = blockIdx.y;
  const int b = nt >> 6, p0 = (nt & 63) * 64;
  const int tid = threadIdx.x;
  const int wv = tid >> 6, lane = tid & 63, lm = lane & 15, quad = lane >> 4;

  const float* xb = x + (size_t)b * CIN * HW + p0;

  floatx4 acc[3][4] = {{{0,0,0,0},{0,0,0,0},{0,0,0,0},{0,0,0,0}},
                       {{0,0,0,0},{0,0,0,0},{0,0,0,0},{0,0,0,0}},
                       {{0,0,0,0},{0,0,0,0},{0,0,0,0},{0,0,0,0}}};

  for (int kq = 0; kq < 4; ++kq) {
    // stage x tile (prev iteration's t readers are behind the Bs-ready
    // barrier; prev Bs-fragment readers are behind the t-ready barrier below)
    #pragma unroll
    for (int i = 0; i < 4; ++i) {
      int ci = tid + i * 256;
      int cc = ci >> 4, p4 = (ci & 15) * 4;
      *(float4*)&t[cc][p4] =
          *(const float4*)(xb + (size_t)(kq * 64 + cc) * HW + p4);
    }
    __syncthreads();   // t ready (also: prev bfr reads done -> Bs writable)
    #pragma unroll
    for (int i = 0; i < 2; ++i) {
      int idx = tid + i * 256;
      int p = idx >> 3, c0 = (idx & 7) * 8;
      half8 v;
      #pragma unroll
      for (int k = 0; k < 8; ++k) v[k] = (_Float16)t[c0 + k][p];
      *(half8*)&Bs[p][c0] = v;
    }
    __syncthreads();   // Bs ready

    // hoist all 8 B fragments once; reused by all 3 m-tiles
    half8 bfr[2][4];
    #pragma unroll
    for (int ks = 0; ks < 2; ++ks)
      #pragma unroll
      for (int ns = 0; ns < 4; ++ns)
        bfr[ks][ns] = *(const half8*)&Bs[ns * 16 + lm][ks * 32 + quad * 8];

    #pragma unroll
    for (int im = 0; im < 3; ++im) {
      const int mt = mg * 3 + im;
      const float wscale = (mt < 2) ? WQSCALE : 1.0f;
      const float* Ag = w + (size_t)(mt * 64 + wv * 16 + lm) * CIN + kq * 64;
      #pragma unroll
      for (int ks = 0; ks < 2; ++ks) {
        const float* srcA = Ag + ks * 32 + quad * 8;
        float4 u0 = *(const float4*)(srcA);
        float4 u1 = *(const float4*)(srcA + 4);
        half8 a = {(_Float16)(u0.x * wscale), (_Float16)(u0.y * wscale),
                   (_Float16)(u0.z * wscale), (_Float16)(u0.w * wscale),
                   (_Float16)(u1.x * wscale), (_Float16)(u1.y * wscale),
                   (_Float16)(u1.z * wscale), (_Float16)(u1.w * wscale)};
        #pragma unroll
        for (int ns = 0; ns < 4; ++ns)
          acc[im][ns] = __builtin_amdgcn_mfma_f32_16x16x32_f16(a, bfr[ks][ns], acc[im][ns], 0, 0, 0);
      }
    }
  }

  #pragma unroll
  for (int im = 0; im < 3; ++im) {
    const int mt = mg * 3 + im;
    const int sec = mt >> 1;                    // 0=Q 1=K 2=V
    const int o_base = (mt & 1) * 64 + wv * 16 + quad * 4;
    const int hh = o_base >> 5, dd = o_base & 31;
    const int bh = b * HEADS + hh;
    if (sec < 2) {
      _Float16* dst = (sec == 0) ? Qw : Kw;
      #pragma unroll
      for (int ns = 0; ns < 4; ++ns) {
        int p = p0 + ns * 16 + lm;
        half4 v = {(_Float16)acc[im][ns][0], (_Float16)acc[im][ns][1],
                   (_Float16)acc[im][ns][2], (_Float16)acc[im][ns][3]};
        *(half4*)(dst + ((size_t)bh * HW + p) * DH + dd) = v;
      }
    } else {
      #pragma unroll
      for (int ns = 0; ns < 4; ++ns) {
        int p = p0 + ns * 16 + lm;
        #pragma unroll
        for (int r = 0; r < 4; ++r)
          Vtw[((size_t)bh * DH + dd + r) * HW + p] = (_Float16)acc[im][ns][r];
      }
    }
  }
}

// ---------------------------------------------------------------------------
// attn: unchanged from R11 (32x32x16, split-K x2, both-hypothesis XOR keys,
// VALU lsum). 64.4 us, conflicts 2.1M (2-way aliasing, throughput-free per
// m136) — LDS work concluded. grid (32, 16, 2) x 256.
// ---------------------------------------------------------------------------
__global__ __launch_bounds__(256) void attn(
    const _Float16* __restrict__ Qw, const _Float16* __restrict__ Kw,
    const _Float16* __restrict__ Vtw, float* __restrict__ Op,
    float* __restrict__ lp)
{
  __shared__ _Float16 ks[2][64][32];          // [phase][k][d]  8 KB
  __shared__ _Float16 vt[2][32][64];          // [phase][d][k]  8 KB

  const int bh = blockIdx.y, qt = blockIdx.x, z = blockIdx.z;
  const int tid = threadIdx.x;
  const int wv = tid >> 6, lane = tid & 63;
  const int l31 = lane & 31, hi = lane >> 5;

  const _Float16* qbase =
      Qw + ((size_t)bh * HW + qt * 128 + wv * 32 + l31) * DH + hi * 8;
  const half8 qb0 = *(const half8*)qbase;        // d = hi*8 + 0..7
  const half8 qb1 = *(const half8*)(qbase + 16); // d = 16 + hi*8 + 0..7

  const floatx16 shift16 = {-SHIFT2,-SHIFT2,-SHIFT2,-SHIFT2,
                            -SHIFT2,-SHIFT2,-SHIFT2,-SHIFT2,
                            -SHIFT2,-SHIFT2,-SHIFT2,-SHIFT2,
                            -SHIFT2,-SHIFT2,-SHIFT2,-SHIFT2};
  floatx16 oT = {0,0,0,0,0,0,0,0,0,0,0,0,0,0,0,0};
  float lsum = 0.0f;

  const _Float16* kbase = Kw  + (size_t)bh * HW * DH + (size_t)z * KHALF * DH;
  const _Float16* vbase = Vtw + (size_t)bh * DH * HW + (size_t)z * KHALF;
  const int kr = tid >> 2, kls = tid & 3;              // K logical slot
  const int vr = tid >> 3, vls = tid & 7;              // V logical slot
  const int kps = (kls ^ (((kr >> 1) ^ (kr >> 3)) & 3)) * 8;  // K phys col
  const int vps = (vls ^ ((vr ^ (vr >> 3)) & 7)) * 8;         // V phys col
  const int kc = kls * 8, vc = vls * 8;                // global offsets

  const int krk = ((l31 >> 1) ^ (l31 >> 3)) & 3;
  const int vrk = (l31 ^ (l31 >> 3)) & 7;

  half8 kA = *(const half8*)(kbase + (size_t)kr * DH + kc);
  half8 vA = *(const half8*)(vbase + (size_t)vr * HW + vc);
  *(half8*)&ks[0][kr][kps] = kA;
  *(half8*)&vt[0][vr][vps] = vA;
  kA = *(const half8*)(kbase + ((size_t)64 + kr) * DH + kc);
  vA = *(const half8*)(vbase + (size_t)vr * HW + 64 + vc);
  __syncthreads();

  for (int it = 0; it < NIT; ++it) {
    const int ph = it & 1, nx = ph ^ 1;

    half8 ka[2][2];
    half8 va[4];
    #pragma unroll
    for (int t = 0; t < 2; ++t)
      #pragma unroll
      for (int d = 0; d < 2; ++d)
        ka[t][d] = *(const half8*)&ks[ph][t * 32 + l31][((d * 2 + hi) ^ krk) * 8];
    #pragma unroll
    for (int k4 = 0; k4 < 4; ++k4)
      va[k4] = *(const half8*)&vt[ph][l31][((k4 * 2 + hi) ^ vrk) * 8];

    *(half8*)&ks[nx][kr][kps] = kA;
    *(half8*)&vt[nx][vr][vps] = vA;
    size_t koff = (size_t)(it + 2) * 64;
    if (koff > KHALF - 64) koff = KHALF - 64;
    kA = *(const half8*)(kbase + (koff + kr) * DH + kc);
    vA = *(const half8*)(vbase + (size_t)vr * HW + koff + vc);

    #pragma unroll
    for (int t = 0; t < 2; ++t) {
      floatx16 sT = __builtin_amdgcn_mfma_f32_32x32x16_f16(ka[t][0], qb0, shift16, 0, 0, 0);
      sT = __builtin_amdgcn_mfma_f32_32x32x16_f16(ka[t][1], qb1, sT, 0, 0, 0);
      float e[16];
      #pragma unroll
      for (int r = 0; r < 16; ++r) e[r] = __builtin_amdgcn_exp2f(sT[r]);
      lsum += (((e[0]+e[1])+(e[2]+e[3]))+((e[4]+e[5])+(e[6]+e[7])))
            + (((e[8]+e[9])+(e[10]+e[11]))+((e[12]+e[13])+(e[14]+e[15])));
      unsigned w0 = pkr(e[0],  e[1]),  w1 = pkr(e[2],  e[3]);
      unsigned w2 = pkr(e[4],  e[5]),  w3 = pkr(e[6],  e[7]);
      unsigned w4 = pkr(e[8],  e[9]),  w5 = pkr(e[10], e[11]);
      unsigned w6 = pkr(e[12], e[13]), w7 = pkr(e[14], e[15]);
      asm("v_permlane32_swap_b32 %0, %1" : "+v"(w0), "+v"(w2));
      asm("v_permlane32_swap_b32 %0, %1" : "+v"(w1), "+v"(w3));
      asm("v_permlane32_swap_b32 %0, %1" : "+v"(w4), "+v"(w6));
      asm("v_permlane32_swap_b32 %0, %1" : "+v"(w5), "+v"(w7));
      uint4v lo4 = {w0, w1, w2, w3}, hi4 = {w4, w5, w6, w7};
      half8 pbLo = __builtin_bit_cast(half8, lo4);
      half8 pbHi = __builtin_bit_cast(half8, hi4);
      oT = __builtin_amdgcn_mfma_f32_32x32x16_f16(va[2*t],     pbLo, oT, 0, 0, 0);
      oT = __builtin_amdgcn_mfma_f32_32x32x16_f16(va[2*t + 1], pbHi, oT, 0, 0, 0);
    }
    __syncthreads();
  }

  lsum += __shfl_xor(lsum, 32, 64);
  const int b = bh >> 2, hh = bh & 3;
  const int row = qt * 128 + wv * 32 + l31;
  float* obase = Op + ((size_t)z * 4 * HW + (size_t)b * HW + row) * HID + hh * DH;
  #pragma unroll
  for (int r0 = 0; r0 < 4; ++r0) {
    float4 v = {oT[4*r0], oT[4*r0+1], oT[4*r0+2], oT[4*r0+3]};
    *(float4*)(obase + 8 * r0 + 4 * hi) = v;
  }
  if (lane < 32)
    lp[(size_t)z * HEADS * 4 * HW + (size_t)bh * HW + row] = lsum;
}

// ---------------------------------------------------------------------------
// out_gemm v3: THIS ROUND — same cut as qkv. A-fragments built in registers
// from L2-hot w_out (float4 pairs + cvt); all 16 B fragments hoisted once
// (64 VGPR) and reused across both m-tiles. As LDS array deleted (36->18 KB),
// barriers 5 -> 2. B-staging (split-K combine + normalize) unchanged.
// grid (2,256) x 256.
// ---------------------------------------------------------------------------
__global__ __launch_bounds__(256) void out_gemm(
    const float* __restrict__ wo, const float* __restrict__ Op,
    const float* __restrict__ lp, const float* __restrict__ bo,
    float* __restrict__ out)
{
  __shared__ _Float16 Bs[64][136];
  __shared__ float inv_l[64][4];
  const int mg = blockIdx.x, nt = blockIdx.y;
  const int b = nt >> 6, p0 = (nt & 63) * 64;
  const int tid = threadIdx.x;
  const int wv = tid >> 6, lane = tid & 63, lm = lane & 15, quad = lane >> 4;

  // combine row sums: inv_l[p][head] = 1/(l_z0 + l_z1)
  {
    const int p = tid >> 2, hh = tid & 3;
    const size_t qi = (size_t)(b * HEADS + hh) * HW + p0 + p;
    inv_l[p][hh] = 1.0f / (lp[qi] + lp[(size_t)HEADS * 4 * HW + qi]);
  }
  __syncthreads();   // inv_l ready

  const float* Bp0 = Op + ((size_t)b * HW + p0) * HID;          // z = 0
  const float* Bp1 = Bp0 + (size_t)4 * HW * HID;                // z = 1

  // stage combined B tile once
  #pragma unroll
  for (int i = 0; i < 4; ++i) {
    int ci = tid + i * 256;
    int r = ci >> 4, c8 = (ci & 15) * 8;
    const float* s0 = Bp0 + (size_t)r * HID + c8;
    const float* s1 = Bp1 + (size_t)r * HID + c8;
    float4 o0 = *(const float4*)(s0);
    float4 o1 = *(const float4*)(s0 + 4);
    float4 o2 = *(const float4*)(s1);
    float4 o3 = *(const float4*)(s1 + 4);
    const float sc = inv_l[r][c8 >> 5];   // 8 cols stay within one head
    half8 hb = {(_Float16)((o0.x + o2.x) * sc), (_Float16)((o0.y + o2.y) * sc),
                (_Float16)((o0.z + o2.z) * sc), (_Float16)((o0.w + o2.w) * sc),
                (_Float16)((o1.x + o3.x) * sc), (_Float16)((o1.y + o3.y) * sc),
                (_Float16)((o1.z + o3.z) * sc), (_Float16)((o1.w + o3.w) * sc)};
    *(half8*)&Bs[r][c8] = hb;
  }
  __syncthreads();   // Bs ready

  // hoist all 16 B fragments once; reused by both m-tiles
  half8 bfr[4][4];
  #pragma unroll
  for (int ks = 0; ks < 4; ++ks)
    #pragma unroll
    for (int ns = 0; ns < 4; ++ns)
      bfr[ks][ns] = *(const half8*)&Bs[ns * 16 + lm][ks * 32 + quad * 8];

  #pragma unroll
  for (int im = 0; im < 2; ++im) {
    const int mt = mg * 2 + im;
    const float* Ag = wo + (size_t)(mt * 64 + wv * 16 + lm) * HID;

    floatx4 acc[4] = {{0,0,0,0},{0,0,0,0},{0,0,0,0},{0,0,0,0}};
    #pragma unroll
    for (int ks = 0; ks < 4; ++ks) {
      const float* srcA = Ag + ks * 32 + quad * 8;
      float4 u0 = *(const float4*)(srcA);
      float4 u1 = *(const float4*)(srcA + 4);
      half8 a = {(_Float16)u0.x, (_Float16)u0.y, (_Float16)u0.z, (_Float16)u0.w,
                 (_Float16)u1.x, (_Float16)u1.y, (_Float16)u1.z, (_Float16)u1.w};
      #pragma unroll
      for (int ns = 0; ns < 4; ++ns)
        acc[ns] = __builtin_amdgcn_mfma_f32_16x16x32_f16(a, bfr[ks][ns], acc[ns], 0, 0, 0);
    }

    // direct stores: C[o][p], o = mt*64 + wv*16 + quad*4 + r, p = p0 + ns*16 + lm
    const int o_loc = wv * 16 + quad * 4;
    #pragma unroll
    for (int r = 0; r < 4; ++r) {
      const int o = mt * 64 + o_loc + r;
      const float bias = bo[o];
      float* dst = out + ((size_t)(b * CIN + o)) * HW + p0 + lm;
      #pragma unroll
      for (int ns = 0; ns < 4; ++ns)
        dst[ns * 16] = acc[ns][r] + bias;
    }
  }
}

// ---------------------------------------------------------------------------
extern "C" void kernel_launch(void* const* d_in, const int* in_sizes, int n_in,
                              void* d_out, int out_size, void* d_ws, size_t ws_size,
                              hipStream_t stream)
{
  const float* x     = (const float*)d_in[0];   // [4,256,64,64]
  const float* w_qkv = (const float*)d_in[1];   // [384,256]
  const float* w_out = (const float*)d_in[2];   // [256,128]
  const float* b_out = (const float*)d_in[3];   // [256]
  float* out = (float*)d_out;

  char* ws = (char*)d_ws;
  _Float16* Qw  = (_Float16*)(ws);               //  4 MB [bh][p][d], log2e-scaled
  _Float16* Kw  = (_Float16*)(ws + (4u  << 20)); //  4 MB [bh][p][d]
  _Float16* Vtw = (_Float16*)(ws + (8u  << 20)); //  4 MB [bh][d][p]
  float*    Op  = (float*)   (ws + (12u << 20)); // 16 MB [2][4][4096][128] f32
  float*    lp  = (float*)   (ws + (28u << 20)); // 0.5MB [2][16][4096] f32

  dim3 blk(256);
  qkv_fused<<<dim3(2, 256), blk, 0, stream>>>(w_qkv, x, Qw, Kw, Vtw);
  attn<<<dim3(32, 16, KSPLIT), blk, 0, stream>>>(Qw, Kw, Vtw, Op, lp);
  out_gemm<<<dim3(2, 256), blk, 0, stream>>>(w_out, Op, lp, b_out, out);
}